// Round 11
// baseline (623.505 us; speedup 1.0000x reference)
//
#include <hip/hip_runtime.h>
#include <math.h>

#define BB 8
#define NN 1024
#define IND 128
#define DD 32
#define HH 8
#define KT 64   // key tile
#define QT 64   // query rows per block

// ---------------------------------------------------------------------------
// ws layout:
//   Q [B,H,N,D] f32, K, V  (2M floats each)
//   A8 [B,N,N] u8          (8.4 MB)
//   sums: double[128] (4 used, 256B apart), cnt: u64[64] (cnt[0], cnt[32])
// ---------------------------------------------------------------------------

__global__ __launch_bounds__(256) void proj_kernel(
    const float* __restrict__ h,
    const float* __restrict__ Wq, const float* __restrict__ bq,
    const float* __restrict__ Wk, const float* __restrict__ bk,
    const float* __restrict__ Wv, const float* __restrict__ bv,
    const int* __restrict__ lengths,
    float* __restrict__ Q, float* __restrict__ K, float* __restrict__ V)
{
    const int cb = blockIdx.x;
    const int rb = blockIdx.y;
    if (((rb & 15) * 64) >= lengths[rb >> 4]) return;

    const int t  = threadIdx.x;
    __shared__ float Xs[64][IND + 1];
    __shared__ float Ws[64][IND + 1];

    const int which = cb >> 2;            // 0=q 1=k 2=v
    const int c0    = (cb & 3) * 64;
    const float* Wsrc = (which == 0) ? Wq : (which == 1) ? Wk : Wv;
    const float* bsrc = (which == 0) ? bq : (which == 1) ? bk : bv;
    float* Out        = (which == 0) ? Q  : (which == 1) ? K  : V;

    #pragma unroll
    for (int i = 0; i < 8; ++i) {
        int e = (i * 256 + t) * 4;
        int r = e >> 7;
        int c = e & 127;
        float4 x = *(const float4*)(&h[(size_t)(rb * 64 + r) * IND + c]);
        Xs[r][c] = x.x; Xs[r][c + 1] = x.y; Xs[r][c + 2] = x.z; Xs[r][c + 3] = x.w;
        float4 w = *(const float4*)(&Wsrc[(size_t)(c0 + r) * IND + c]);
        Ws[r][c] = w.x; Ws[r][c + 1] = w.y; Ws[r][c + 2] = w.z; Ws[r][c + 3] = w.w;
    }
    __syncthreads();

    const int tr = (t >> 4) * 4;
    const int tc = (t & 15) * 4;
    float acc[4][4] = {};
    #pragma unroll 4
    for (int k = 0; k < IND; ++k) {
        float a0 = Xs[tr + 0][k], a1 = Xs[tr + 1][k], a2 = Xs[tr + 2][k], a3 = Xs[tr + 3][k];
        float w0 = Ws[tc + 0][k], w1 = Ws[tc + 1][k], w2 = Ws[tc + 2][k], w3 = Ws[tc + 3][k];
        acc[0][0] = fmaf(a0, w0, acc[0][0]); acc[0][1] = fmaf(a0, w1, acc[0][1]);
        acc[0][2] = fmaf(a0, w2, acc[0][2]); acc[0][3] = fmaf(a0, w3, acc[0][3]);
        acc[1][0] = fmaf(a1, w0, acc[1][0]); acc[1][1] = fmaf(a1, w1, acc[1][1]);
        acc[1][2] = fmaf(a1, w2, acc[1][2]); acc[1][3] = fmaf(a1, w3, acc[1][3]);
        acc[2][0] = fmaf(a2, w0, acc[2][0]); acc[2][1] = fmaf(a2, w1, acc[2][1]);
        acc[2][2] = fmaf(a2, w2, acc[2][2]); acc[2][3] = fmaf(a2, w3, acc[2][3]);
        acc[3][0] = fmaf(a3, w0, acc[3][0]); acc[3][1] = fmaf(a3, w1, acc[3][1]);
        acc[3][2] = fmaf(a3, w2, acc[3][2]); acc[3][3] = fmaf(a3, w3, acc[3][3]);
    }

    #pragma unroll
    for (int i = 0; i < 4; ++i) {
        int r = rb * 64 + tr + i;
        int bb = r >> 10, n = r & 1023;
        #pragma unroll
        for (int j = 0; j < 4; ++j) {
            int o = tc + j + c0;
            int hh = o >> 5, dd = o & 31;
            Out[(((size_t)bb * HH + hh) * NN + n) * DD + dd] = acc[i][j] + bsrc[o];
        }
    }
}

__global__ __launch_bounds__(256) void pack_kernel(
    const int* __restrict__ A, unsigned char* __restrict__ A8,
    unsigned long long* __restrict__ cnt)
{
    const int NT = (BB * NN * NN) / 4;
    unsigned c1 = 0, c2 = 0;
    for (int idx = blockIdx.x * 256 + threadIdx.x; idx < NT; idx += gridDim.x * 256) {
        int4 a = *(const int4*)&A[(size_t)idx * 4];
        unsigned packed = (unsigned)(a.x & 0xff) | ((unsigned)(a.y & 0xff) << 8) |
                          ((unsigned)(a.z & 0xff) << 16) | ((unsigned)(a.w & 0xff) << 24);
        *(unsigned*)&A8[(size_t)idx * 4] = packed;
        c1 += (a.x == 1) + (a.y == 1) + (a.z == 1) + (a.w == 1);
        c2 += (a.x > 1) + (a.y > 1) + (a.z > 1) + (a.w > 1);
    }
    #pragma unroll
    for (int off = 32; off; off >>= 1) {
        c1 += __shfl_down(c1, off);
        c2 += __shfl_down(c2, off);
    }
    __shared__ unsigned r1[4], r2[4];
    const int wave = threadIdx.x >> 6;
    if ((threadIdx.x & 63) == 0) { r1[wave] = c1; r2[wave] = c2; }
    __syncthreads();
    if (threadIdx.x == 0) {
        unsigned long long t1 = (unsigned long long)r1[0] + r1[1] + r1[2] + r1[3];
        unsigned long long t2 = (unsigned long long)r2[0] + r2[1] + r2[2] + r2[3];
        atomicAdd(&cnt[0], t1);
        atomicAdd(&cnt[32], t2);
    }
}

// R11 attn: intra-block K-split. R10 profile: VALUBusy 25%, Occupancy 9.6% ->
// tail-bound on longest-len batch (16 serial k-tiles, ~1 wave/SIMD at the end).
// Now 512 threads = 2 halves of 256; half h does k-tiles 2*it+h -> critical
// path 16->8 tiles. Halves merge (m,l,acc,sums) via LDS at the end. LDS 56.4KB
// -> 2 blocks/CU x 8 waves = 16 waves/CU (same busy-phase TLP as R10).
__global__ __launch_bounds__(512) void attn_kernel(
    const float* __restrict__ Q, const float* __restrict__ Kg, const float* __restrict__ Vg,
    const unsigned char* __restrict__ A8,
    const int* __restrict__ lengths, const float* __restrict__ alpha,
    float* __restrict__ out, double* __restrict__ sums)
{
    const int bid = blockIdx.x;
    const int qt = bid & 15;
    const int hh = (bid >> 4) & 7;
    const int b  = bid >> 7;
    const int t  = threadIdx.x;
    const int half = t >> 8;        // 0/1: even/odd k-tiles
    const int t2 = t & 255;
    const int qg = t2 >> 3;         // 0..31
    const int lane8 = t2 & 7;

    const int len = lengths[b];
    const size_t base = ((size_t)b * HH + hh) * NN * DD;
    const int gq0 = qt * QT + qg;
    const int gq1 = gq0 + 32;

    if (qt * QT >= len) {           // fully padded q-block: zeros, done
        if (t < 256) {
            float4 z = make_float4(0.f, 0.f, 0.f, 0.f);
            *(float4*)&out[base + (size_t)gq0 * DD + lane8 * 4] = z;
            *(float4*)&out[base + (size_t)gq1 * DD + lane8 * 4] = z;
        }
        return;
    }

    // Manual LDS layout (bytes):
    //   0      Qs[64][36]f           9216
    //   9216   Ks half0/half1        2x9216
    //   27648  Vs half0/half1        2x9216
    //   46080  As half0/half1        2x5120   <- aliased by mrg[64][40]f after k-loop
    //   56320  redp[4][8]f           128      total 56448
    __shared__ __align__(16) char smem[56448];
    float (*Qs)[36]          = (float (*)[36])smem;
    float (*Ks)[36]          = (float (*)[36])(smem + 9216 + half * 9216);
    float (*Vs)[36]          = (float (*)[36])(smem + 27648 + half * 9216);
    unsigned char (*Asl)[80] = (unsigned char (*)[80])(smem + 46080 + half * 5120);
    float* mrg  = (float*)(smem + 46080);
    float* redp = (float*)(smem + 56320);

    const float al  = alpha[0];
    const float l2a = __log2f(al);
    const float scale = 0.17677669529663687f;   // 1/sqrt(32)

    // permuted staging: quad = (r+c)%8 distinct per wave -> no write conflict
    const int sr = t2 >> 3;
    const int sc = ((t2 & 7) - sr) & 7;

    if (t < 256) {                  // half0 stages Q (covered by first in-loop barrier)
        #pragma unroll
        for (int i = 0; i < 2; ++i) {
            int r = i * 32 + sr;
            float4 v = *(const float4*)&Q[base + (size_t)(qt * QT + r) * DD + sc * 4];
            v.x *= scale; v.y *= scale; v.z *= scale; v.w *= scale;
            *(float4*)&Qs[r][sc * 4] = v;
        }
    }

    float m0 = -1e30f, m1 = -1e30f, l0 = 0.f, l1 = 0.f;
    float acc0[32], acc1[32];
    #pragma unroll
    for (int d = 0; d < 32; ++d) { acc0[d] = 0.f; acc1[d] = 0.f; }
    float pr0_1 = 0.f, pr0_2 = 0.f, po0_1 = 0.f, po0_2 = 0.f;
    float pr1_1 = 0.f, pr1_2 = 0.f, po1_1 = 0.f, po1_2 = 0.f;

    const int ntiles = (len + KT - 1) / KT;
    const int nit = (ntiles + 1) >> 1;      // equalized trip count (both halves)

    for (int it = 0; it < nit; ++it) {
        const int j0  = (2 * it + half) * KT;   // real tile start (masking)
        const int j0c = (j0 < len) ? j0 : 0;    // clamped for safe staging
        __syncthreads();
        #pragma unroll
        for (int i = 0; i < 2; ++i) {
            int r = i * 32 + sr;
            *(float4*)&Ks[r][sc * 4] = *(const float4*)&Kg[base + (size_t)(j0c + r) * DD + sc * 4];
            *(float4*)&Vs[r][sc * 4] = *(const float4*)&Vg[base + (size_t)(j0c + r) * DD + sc * 4];
        }
        {
            int r = t2 >> 2, c = (t2 & 3) * 16;
            *(int4*)&Asl[r][c] = *(const int4*)&A8[((size_t)b * NN + qt * QT + r) * NN + j0c + c];
        }
        __syncthreads();

        float s0[8], s1[8];
        #pragma unroll
        for (int e = 0; e < 8; ++e) { s0[e] = 0.f; s1[e] = 0.f; }
        #pragma unroll
        for (int i = 0; i < 8; ++i) {
            float4 qa = *(const float4*)&Qs[qg][i * 4];
            float4 qb = *(const float4*)&Qs[qg + 32][i * 4];
            #pragma unroll
            for (int e = 0; e < 8; ++e) {
                float4 kv = *(const float4*)&Ks[e * 8 + lane8][i * 4];
                s0[e] = fmaf(qa.x, kv.x, s0[e]); s0[e] = fmaf(qa.y, kv.y, s0[e]);
                s0[e] = fmaf(qa.z, kv.z, s0[e]); s0[e] = fmaf(qa.w, kv.w, s0[e]);
                s1[e] = fmaf(qb.x, kv.x, s1[e]); s1[e] = fmaf(qb.y, kv.y, s1[e]);
                s1[e] = fmaf(qb.z, kv.z, s1[e]); s1[e] = fmaf(qb.w, kv.w, s1[e]);
            }
        }

        float tm0 = -INFINITY, tm1 = -INFINITY;
        #pragma unroll
        for (int e = 0; e < 8; ++e) {
            bool valid = (j0 + e * 8 + lane8) < len;   // phantom tiles fully masked
            s0[e] = valid ? s0[e] : -INFINITY;
            s1[e] = valid ? s1[e] : -INFINITY;
            tm0 = fmaxf(tm0, s0[e]); tm1 = fmaxf(tm1, s1[e]);
        }
        #pragma unroll
        for (int off = 1; off < 8; off <<= 1) {
            tm0 = fmaxf(tm0, __shfl_xor(tm0, off, 8));
            tm1 = fmaxf(tm1, __shfl_xor(tm1, off, 8));
        }
        if (tm0 > m0) {
            float scl = __expf(m0 - tm0);
            l0 *= scl; pr0_1 *= scl; pr0_2 *= scl; po0_1 *= scl; po0_2 *= scl;
            #pragma unroll
            for (int d = 0; d < 32; ++d) acc0[d] *= scl;
            m0 = tm0;
        }
        if (tm1 > m1) {
            float scl = __expf(m1 - tm1);
            l1 *= scl; pr1_1 *= scl; pr1_2 *= scl; po1_1 *= scl; po1_2 *= scl;
            #pragma unroll
            for (int d = 0; d < 32; ++d) acc1[d] *= scl;
            m1 = tm1;
        }

        #pragma unroll
        for (int e = 0; e < 8; ++e) {
            int j = e * 8 + lane8;
            float pe0 = __expf(s0[e] - m0);
            float pe1 = __expf(s1[e] - m1);
            l0 += pe0; l1 += pe1;
            int a0 = Asl[qg][j], a1 = Asl[qg + 32][j];
            float w0 = exp2f((float)a0 * l2a);
            float w1 = exp2f((float)a1 * l2a);
            float pw0 = pe0 * w0, pw1 = pe1 * w1;
            pr0_1 += (a0 == 1) ? pe0 : 0.f;  pr0_2 += (a0 > 1) ? pe0 : 0.f;
            po0_1 += (a0 == 1) ? pw0 : 0.f;  po0_2 += (a0 > 1) ? pw0 : 0.f;
            pr1_1 += (a1 == 1) ? pe1 : 0.f;  pr1_2 += (a1 > 1) ? pe1 : 0.f;
            po1_1 += (a1 == 1) ? pw1 : 0.f;  po1_2 += (a1 > 1) ? pw1 : 0.f;
            s0[e] = pw0; s1[e] = pw1;
        }

        #pragma unroll
        for (int e = 0; e < 8; ++e) {
            float pw0 = s0[e], pw1 = s1[e];
            #pragma unroll
            for (int i = 0; i < 8; ++i) {
                float4 vv = *(const float4*)&Vs[e * 8 + lane8][i * 4];
                acc0[i * 4 + 0] = fmaf(pw0, vv.x, acc0[i * 4 + 0]);
                acc0[i * 4 + 1] = fmaf(pw0, vv.y, acc0[i * 4 + 1]);
                acc0[i * 4 + 2] = fmaf(pw0, vv.z, acc0[i * 4 + 2]);
                acc0[i * 4 + 3] = fmaf(pw0, vv.w, acc0[i * 4 + 3]);
                acc1[i * 4 + 0] = fmaf(pw1, vv.x, acc1[i * 4 + 0]);
                acc1[i * 4 + 1] = fmaf(pw1, vv.y, acc1[i * 4 + 1]);
                acc1[i * 4 + 2] = fmaf(pw1, vv.z, acc1[i * 4 + 2]);
                acc1[i * 4 + 3] = fmaf(pw1, vv.w, acc1[i * 4 + 3]);
            }
        }
    }

    // per-half: reduce everything to row level across the 8-lane group
    #pragma unroll
    for (int off = 1; off < 8; off <<= 1) {
        l0 += __shfl_xor(l0, off, 8);       l1 += __shfl_xor(l1, off, 8);
        pr0_1 += __shfl_xor(pr0_1, off, 8); pr0_2 += __shfl_xor(pr0_2, off, 8);
        po0_1 += __shfl_xor(po0_1, off, 8); po0_2 += __shfl_xor(po0_2, off, 8);
        pr1_1 += __shfl_xor(pr1_1, off, 8); pr1_2 += __shfl_xor(pr1_2, off, 8);
        po1_1 += __shfl_xor(po1_1, off, 8); po1_2 += __shfl_xor(po1_2, off, 8);
        #pragma unroll
        for (int d = 0; d < 32; ++d) {
            acc0[d] += __shfl_xor(acc0[d], off, 8);
            acc1[d] += __shfl_xor(acc1[d], off, 8);
        }
    }

    __syncthreads();                        // last use of As region done
    if (half == 1 && lane8 == 0) {          // publish half1 row states into mrg (aliases As)
        float* r = &mrg[(size_t)qg * 40];
        r[0] = m0; r[1] = l0; r[2] = pr0_1; r[3] = pr0_2; r[4] = po0_1; r[5] = po0_2;
        #pragma unroll
        for (int d = 0; d < 32; ++d) r[6 + d] = acc0[d];
        float* r2 = &mrg[(size_t)(qg + 32) * 40];
        r2[0] = m1; r2[1] = l1; r2[2] = pr1_1; r2[3] = pr1_2; r2[4] = po1_1; r2[5] = po1_2;
        #pragma unroll
        for (int d = 0; d < 32; ++d) r2[6 + d] = acc1[d];
    }
    __syncthreads();

    float v1 = 0.f, v2 = 0.f, v3 = 0.f, v4 = 0.f;
    if (half == 0) {
        const int dsl = lane8 * 4;
        {   // row gq0 (state 0)
            const float* r = &mrg[(size_t)qg * 40];
            float mB = r[0], LB = r[1];
            float ms = fmaxf(m0, mB);
            float fA = __expf(m0 - ms), fB = __expf(mB - ms);
            float L = l0 * fA + LB * fB;
            float inv = (gq0 < len) ? 1.f / L : 0.f;
            float4 o;
            o.x = (acc0[dsl + 0] * fA + r[6 + dsl + 0] * fB) * inv;
            o.y = (acc0[dsl + 1] * fA + r[6 + dsl + 1] * fB) * inv;
            o.z = (acc0[dsl + 2] * fA + r[6 + dsl + 2] * fB) * inv;
            o.w = (acc0[dsl + 3] * fA + r[6 + dsl + 3] * fB) * inv;
            *(float4*)&out[base + (size_t)gq0 * DD + dsl] = o;
            if (lane8 == 0) {
                v1 += (pr0_1 * fA + r[2] * fB) * inv;
                v2 += (pr0_2 * fA + r[3] * fB) * inv;
                v3 += (po0_1 * fA + r[4] * fB) * inv;
                v4 += (po0_2 * fA + r[5] * fB) * inv;
            }
        }
        {   // row gq1 (state 1)
            const float* r = &mrg[(size_t)(qg + 32) * 40];
            float mB = r[0], LB = r[1];
            float ms = fmaxf(m1, mB);
            float fA = __expf(m1 - ms), fB = __expf(mB - ms);
            float L = l1 * fA + LB * fB;
            float inv = (gq1 < len) ? 1.f / L : 0.f;
            float4 o;
            o.x = (acc1[dsl + 0] * fA + r[6 + dsl + 0] * fB) * inv;
            o.y = (acc1[dsl + 1] * fA + r[6 + dsl + 1] * fB) * inv;
            o.z = (acc1[dsl + 2] * fA + r[6 + dsl + 2] * fB) * inv;
            o.w = (acc1[dsl + 3] * fA + r[6 + dsl + 3] * fB) * inv;
            *(float4*)&out[base + (size_t)gq1 * DD + dsl] = o;
            if (lane8 == 0) {
                v1 += (pr1_1 * fA + r[2] * fB) * inv;
                v2 += (pr1_2 * fA + r[3] * fB) * inv;
                v3 += (po1_1 * fA + r[4] * fB) * inv;
                v4 += (po1_2 * fA + r[5] * fB) * inv;
            }
        }
    }

    // block scalar reduction: 64-lane butterfly per wave -> redp[4][8] -> 4 atomics
    #pragma unroll
    for (int off = 1; off < 64; off <<= 1) {
        v1 += __shfl_xor(v1, off);
        v2 += __shfl_xor(v2, off);
        v3 += __shfl_xor(v3, off);
        v4 += __shfl_xor(v4, off);
    }
    const int wv = t >> 6;                  // 0..7
    __syncthreads();                        // mrg reads done before redp writes (redp separate, but order anyway)
    if ((t & 63) == 0) {
        redp[0 * 8 + wv] = v1; redp[1 * 8 + wv] = v2;
        redp[2 * 8 + wv] = v3; redp[3 * 8 + wv] = v4;
    }
    __syncthreads();
    if (t < 4) {
        float s = 0.f;
        #pragma unroll
        for (int w = 0; w < 8; ++w) s += redp[t * 8 + w];
        atomicAdd(&sums[t * 32], (double)s);   // 256B apart: parallel chains
    }
}

__global__ void fin_kernel(const double* __restrict__ sums,
                           const unsigned long long* __restrict__ cnt,
                           float* __restrict__ outtail)
{
    if (threadIdx.x == 0) {
        double c1 = (double)(cnt[0] * (unsigned long long)HH);
        double c2 = (double)(cnt[32] * (unsigned long long)HH);
        outtail[0] = (float)(sums[0]  / c1);
        outtail[1] = (float)(sums[32] / c2);
        outtail[2] = (float)(sums[64] / c1);
        outtail[3] = (float)(sums[96] / c2);
    }
}

extern "C" void kernel_launch(void* const* d_in, const int* in_sizes, int n_in,
                              void* d_out, int out_size, void* d_ws, size_t ws_size,
                              hipStream_t stream)
{
    const float* h   = (const float*)d_in[0];
    const int* A     = (const int*)d_in[1];
    const int* lens  = (const int*)d_in[2];
    const float* alp = (const float*)d_in[3];
    const float* Wq  = (const float*)d_in[4];
    const float* bq  = (const float*)d_in[5];
    const float* Wk  = (const float*)d_in[6];
    const float* bk  = (const float*)d_in[7];
    const float* Wv  = (const float*)d_in[8];
    const float* bv  = (const float*)d_in[9];

    float* outF = (float*)d_out;

    const size_t qkv = (size_t)BB * HH * NN * DD;
    float* Qw = (float*)d_ws;
    float* Kw = Qw + qkv;
    float* Vw = Kw + qkv;
    unsigned char* A8 = (unsigned char*)(Vw + qkv);
    double* sums = (double*)(A8 + (size_t)BB * NN * NN);
    unsigned long long* cnt = (unsigned long long*)(sums + 128);

    (void)hipMemsetAsync(sums, 0, 128 * sizeof(double) + 64 * sizeof(unsigned long long), stream);

    proj_kernel<<<dim3(12, 128), 256, 0, stream>>>(h, Wq, bq, Wk, bk, Wv, bv, lens, Qw, Kw, Vw);
    pack_kernel<<<1024, 256, 0, stream>>>(A, A8, cnt);
    attn_kernel<<<BB * HH * (NN / QT), 512, 0, stream>>>(Qw, Kw, Vw, A8, lens, alp, outF, sums);
    fin_kernel<<<1, 64, 0, stream>>>(sums, cnt, outF + qkv);
}

// Round 12
// 255.400 us; speedup vs baseline: 2.4413x; 2.4413x over previous
//
#include <hip/hip_runtime.h>
#include <math.h>

#define BB 8
#define NN 1024
#define IND 128
#define DD 32
#define HH 8
#define KT 64   // key tile
#define QT 64   // query rows per block

// ---------------------------------------------------------------------------
// ws layout:
//   Q [B,H,N,D] f32, K, V  (8.39 MB each)
//   A8 [B,N,N] u8          (8.39 MB)
//   sums: double[128] (4 used, 256B apart), cnt: u64[64] (cnt[0], cnt[32])
//   part: float[2048][64][40]  (21 MB; only if ws_size permits -> split path)
// R11 post-mortem: 512-thr intra-block K-split spilled accumulators (VGPR
// capped 128; WRITE_SIZE 8->686MB = scratch RMW every rescale). R12: grid-
// level K-split keeps the proven 256-thr/VGPR-100 inner loop untouched.
// ---------------------------------------------------------------------------

__global__ __launch_bounds__(256) void proj_kernel(
    const float* __restrict__ h,
    const float* __restrict__ Wq, const float* __restrict__ bq,
    const float* __restrict__ Wk, const float* __restrict__ bk,
    const float* __restrict__ Wv, const float* __restrict__ bv,
    const int* __restrict__ lengths,
    float* __restrict__ Q, float* __restrict__ K, float* __restrict__ V)
{
    const int cb = blockIdx.x;
    const int rb = blockIdx.y;
    if (((rb & 15) * 64) >= lengths[rb >> 4]) return;

    const int t  = threadIdx.x;
    __shared__ float Xs[64][IND + 1];
    __shared__ float Ws[64][IND + 1];

    const int which = cb >> 2;            // 0=q 1=k 2=v
    const int c0    = (cb & 3) * 64;
    const float* Wsrc = (which == 0) ? Wq : (which == 1) ? Wk : Wv;
    const float* bsrc = (which == 0) ? bq : (which == 1) ? bk : bv;
    float* Out        = (which == 0) ? Q  : (which == 1) ? K  : V;

    #pragma unroll
    for (int i = 0; i < 8; ++i) {
        int e = (i * 256 + t) * 4;
        int r = e >> 7;
        int c = e & 127;
        float4 x = *(const float4*)(&h[(size_t)(rb * 64 + r) * IND + c]);
        Xs[r][c] = x.x; Xs[r][c + 1] = x.y; Xs[r][c + 2] = x.z; Xs[r][c + 3] = x.w;
        float4 w = *(const float4*)(&Wsrc[(size_t)(c0 + r) * IND + c]);
        Ws[r][c] = w.x; Ws[r][c + 1] = w.y; Ws[r][c + 2] = w.z; Ws[r][c + 3] = w.w;
    }
    __syncthreads();

    const int tr = (t >> 4) * 4;
    const int tc = (t & 15) * 4;
    float acc[4][4] = {};
    #pragma unroll 4
    for (int k = 0; k < IND; ++k) {
        float a0 = Xs[tr + 0][k], a1 = Xs[tr + 1][k], a2 = Xs[tr + 2][k], a3 = Xs[tr + 3][k];
        float w0 = Ws[tc + 0][k], w1 = Ws[tc + 1][k], w2 = Ws[tc + 2][k], w3 = Ws[tc + 3][k];
        acc[0][0] = fmaf(a0, w0, acc[0][0]); acc[0][1] = fmaf(a0, w1, acc[0][1]);
        acc[0][2] = fmaf(a0, w2, acc[0][2]); acc[0][3] = fmaf(a0, w3, acc[0][3]);
        acc[1][0] = fmaf(a1, w0, acc[1][0]); acc[1][1] = fmaf(a1, w1, acc[1][1]);
        acc[1][2] = fmaf(a1, w2, acc[1][2]); acc[1][3] = fmaf(a1, w3, acc[1][3]);
        acc[2][0] = fmaf(a2, w0, acc[2][0]); acc[2][1] = fmaf(a2, w1, acc[2][1]);
        acc[2][2] = fmaf(a2, w2, acc[2][2]); acc[2][3] = fmaf(a2, w3, acc[2][3]);
        acc[3][0] = fmaf(a3, w0, acc[3][0]); acc[3][1] = fmaf(a3, w1, acc[3][1]);
        acc[3][2] = fmaf(a3, w2, acc[3][2]); acc[3][3] = fmaf(a3, w3, acc[3][3]);
    }

    #pragma unroll
    for (int i = 0; i < 4; ++i) {
        int r = rb * 64 + tr + i;
        int bb = r >> 10, n = r & 1023;
        #pragma unroll
        for (int j = 0; j < 4; ++j) {
            int o = tc + j + c0;
            int hh = o >> 5, dd = o & 31;
            Out[(((size_t)bb * HH + hh) * NN + n) * DD + dd] = acc[i][j] + bsrc[o];
        }
    }
}

__global__ __launch_bounds__(256) void pack_kernel(
    const int* __restrict__ A, unsigned char* __restrict__ A8,
    unsigned long long* __restrict__ cnt)
{
    const int NT = (BB * NN * NN) / 4;
    unsigned c1 = 0, c2 = 0;
    for (int idx = blockIdx.x * 256 + threadIdx.x; idx < NT; idx += gridDim.x * 256) {
        int4 a = *(const int4*)&A[(size_t)idx * 4];
        unsigned packed = (unsigned)(a.x & 0xff) | ((unsigned)(a.y & 0xff) << 8) |
                          ((unsigned)(a.z & 0xff) << 16) | ((unsigned)(a.w & 0xff) << 24);
        *(unsigned*)&A8[(size_t)idx * 4] = packed;
        c1 += (a.x == 1) + (a.y == 1) + (a.z == 1) + (a.w == 1);
        c2 += (a.x > 1) + (a.y > 1) + (a.z > 1) + (a.w > 1);
    }
    #pragma unroll
    for (int off = 32; off; off >>= 1) {
        c1 += __shfl_down(c1, off);
        c2 += __shfl_down(c2, off);
    }
    __shared__ unsigned r1[4], r2[4];
    const int wave = threadIdx.x >> 6;
    if ((threadIdx.x & 63) == 0) { r1[wave] = c1; r2[wave] = c2; }
    __syncthreads();
    if (threadIdx.x == 0) {
        unsigned long long t1 = (unsigned long long)r1[0] + r1[1] + r1[2] + r1[3];
        unsigned long long t2 = (unsigned long long)r2[0] + r2[1] + r2[2] + r2[3];
        atomicAdd(&cnt[0], t1);
        atomicAdd(&cnt[32], t2);
    }
}

// Shared inner-loop macro body is avoided; the two attn variants are kept as
// near-identical copies of the proven R10 loop (256 thr, VGPR~100, no spill).

// ---- variant A: single-pass (R10, fallback when ws too small) --------------
__global__ __launch_bounds__(256) void attn_kernel(
    const float* __restrict__ Q, const float* __restrict__ Kg, const float* __restrict__ Vg,
    const unsigned char* __restrict__ A8,
    const int* __restrict__ lengths, const float* __restrict__ alpha,
    float* __restrict__ out, double* __restrict__ sums)
{
    const int bid = blockIdx.x;
    const int qt = bid & 15;
    const int hh = (bid >> 4) & 7;
    const int b  = bid >> 7;
    const int t  = threadIdx.x;
    const int qg = t >> 3;
    const int lane8 = t & 7;

    const int len = lengths[b];
    const size_t base = ((size_t)b * HH + hh) * NN * DD;
    const int gq0 = qt * QT + qg;
    const int gq1 = gq0 + 32;

    if (qt * QT >= len) {
        float4 z = make_float4(0.f, 0.f, 0.f, 0.f);
        *(float4*)&out[base + (size_t)gq0 * DD + lane8 * 4] = z;
        *(float4*)&out[base + (size_t)gq1 * DD + lane8 * 4] = z;
        return;
    }

    __shared__ float Qs[QT][36];
    __shared__ float Ks[KT][36];
    __shared__ float Vs[KT][36];
    __shared__ unsigned char As[QT][80];
    __shared__ float red4[4][4];

    const float al  = alpha[0];
    const float l2a = __log2f(al);
    const float scale = 0.17677669529663687f;

    const int sr = t >> 3;
    const int sc = ((t & 7) - sr) & 7;

    #pragma unroll
    for (int i = 0; i < 2; ++i) {
        int r = i * 32 + sr;
        float4 v = *(const float4*)&Q[base + (size_t)(qt * QT + r) * DD + sc * 4];
        v.x *= scale; v.y *= scale; v.z *= scale; v.w *= scale;
        *(float4*)&Qs[r][sc * 4] = v;
    }

    float m0 = -1e30f, m1 = -1e30f, l0 = 0.f, l1 = 0.f;
    float acc0[32], acc1[32];
    #pragma unroll
    for (int d = 0; d < 32; ++d) { acc0[d] = 0.f; acc1[d] = 0.f; }
    float pr0_1 = 0.f, pr0_2 = 0.f, po0_1 = 0.f, po0_2 = 0.f;
    float pr1_1 = 0.f, pr1_2 = 0.f, po1_1 = 0.f, po1_2 = 0.f;

    for (int j0 = 0; j0 < len; j0 += KT) {
        __syncthreads();
        #pragma unroll
        for (int i = 0; i < 2; ++i) {
            int r = i * 32 + sr;
            *(float4*)&Ks[r][sc * 4] = *(const float4*)&Kg[base + (size_t)(j0 + r) * DD + sc * 4];
            *(float4*)&Vs[r][sc * 4] = *(const float4*)&Vg[base + (size_t)(j0 + r) * DD + sc * 4];
        }
        {
            int r = t >> 2, c = (t & 3) * 16;
            *(int4*)&As[r][c] = *(const int4*)&A8[((size_t)b * NN + qt * QT + r) * NN + j0 + c];
        }
        __syncthreads();

        float s0[8], s1[8];
        #pragma unroll
        for (int e = 0; e < 8; ++e) { s0[e] = 0.f; s1[e] = 0.f; }
        #pragma unroll
        for (int i = 0; i < 8; ++i) {
            float4 qa = *(const float4*)&Qs[qg][i * 4];
            float4 qb = *(const float4*)&Qs[qg + 32][i * 4];
            #pragma unroll
            for (int e = 0; e < 8; ++e) {
                float4 kv = *(const float4*)&Ks[e * 8 + lane8][i * 4];
                s0[e] = fmaf(qa.x, kv.x, s0[e]); s0[e] = fmaf(qa.y, kv.y, s0[e]);
                s0[e] = fmaf(qa.z, kv.z, s0[e]); s0[e] = fmaf(qa.w, kv.w, s0[e]);
                s1[e] = fmaf(qb.x, kv.x, s1[e]); s1[e] = fmaf(qb.y, kv.y, s1[e]);
                s1[e] = fmaf(qb.z, kv.z, s1[e]); s1[e] = fmaf(qb.w, kv.w, s1[e]);
            }
        }

        float tm0 = -INFINITY, tm1 = -INFINITY;
        #pragma unroll
        for (int e = 0; e < 8; ++e) {
            bool valid = (j0 + e * 8 + lane8) < len;
            s0[e] = valid ? s0[e] : -INFINITY;
            s1[e] = valid ? s1[e] : -INFINITY;
            tm0 = fmaxf(tm0, s0[e]); tm1 = fmaxf(tm1, s1[e]);
        }
        #pragma unroll
        for (int off = 1; off < 8; off <<= 1) {
            tm0 = fmaxf(tm0, __shfl_xor(tm0, off, 8));
            tm1 = fmaxf(tm1, __shfl_xor(tm1, off, 8));
        }
        if (tm0 > m0) {
            float scl = __expf(m0 - tm0);
            l0 *= scl; pr0_1 *= scl; pr0_2 *= scl; po0_1 *= scl; po0_2 *= scl;
            #pragma unroll
            for (int d = 0; d < 32; ++d) acc0[d] *= scl;
            m0 = tm0;
        }
        if (tm1 > m1) {
            float scl = __expf(m1 - tm1);
            l1 *= scl; pr1_1 *= scl; pr1_2 *= scl; po1_1 *= scl; po1_2 *= scl;
            #pragma unroll
            for (int d = 0; d < 32; ++d) acc1[d] *= scl;
            m1 = tm1;
        }

        #pragma unroll
        for (int e = 0; e < 8; ++e) {
            int j = e * 8 + lane8;
            float pe0 = __expf(s0[e] - m0);
            float pe1 = __expf(s1[e] - m1);
            l0 += pe0; l1 += pe1;
            int a0 = As[qg][j], a1 = As[qg + 32][j];
            float w0 = exp2f((float)a0 * l2a);
            float w1 = exp2f((float)a1 * l2a);
            float pw0 = pe0 * w0, pw1 = pe1 * w1;
            pr0_1 += (a0 == 1) ? pe0 : 0.f;  pr0_2 += (a0 > 1) ? pe0 : 0.f;
            po0_1 += (a0 == 1) ? pw0 : 0.f;  po0_2 += (a0 > 1) ? pw0 : 0.f;
            pr1_1 += (a1 == 1) ? pe1 : 0.f;  pr1_2 += (a1 > 1) ? pe1 : 0.f;
            po1_1 += (a1 == 1) ? pw1 : 0.f;  po1_2 += (a1 > 1) ? pw1 : 0.f;
            s0[e] = pw0; s1[e] = pw1;
        }

        #pragma unroll
        for (int e = 0; e < 8; ++e) {
            float pw0 = s0[e], pw1 = s1[e];
            #pragma unroll
            for (int i = 0; i < 8; ++i) {
                float4 vv = *(const float4*)&Vs[e * 8 + lane8][i * 4];
                acc0[i * 4 + 0] = fmaf(pw0, vv.x, acc0[i * 4 + 0]);
                acc0[i * 4 + 1] = fmaf(pw0, vv.y, acc0[i * 4 + 1]);
                acc0[i * 4 + 2] = fmaf(pw0, vv.z, acc0[i * 4 + 2]);
                acc0[i * 4 + 3] = fmaf(pw0, vv.w, acc0[i * 4 + 3]);
                acc1[i * 4 + 0] = fmaf(pw1, vv.x, acc1[i * 4 + 0]);
                acc1[i * 4 + 1] = fmaf(pw1, vv.y, acc1[i * 4 + 1]);
                acc1[i * 4 + 2] = fmaf(pw1, vv.z, acc1[i * 4 + 2]);
                acc1[i * 4 + 3] = fmaf(pw1, vv.w, acc1[i * 4 + 3]);
            }
        }
    }

    #pragma unroll
    for (int off = 1; off < 8; off <<= 1) {
        l0 += __shfl_xor(l0, off, 8);
        l1 += __shfl_xor(l1, off, 8);
    }
    const float inv0 = (gq0 < len) ? 1.f / l0 : 0.f;
    const float inv1 = (gq1 < len) ? 1.f / l1 : 0.f;

    #pragma unroll
    for (int off = 1; off < 8; off <<= 1) {
        #pragma unroll
        for (int d = 0; d < 32; ++d) {
            acc0[d] += __shfl_xor(acc0[d], off, 8);
            acc1[d] += __shfl_xor(acc1[d], off, 8);
        }
    }
    if (lane8 == 0) {
        #pragma unroll
        for (int i = 0; i < 8; ++i) {
            *(float4*)&out[base + (size_t)gq0 * DD + i * 4] =
                make_float4(acc0[i * 4 + 0] * inv0, acc0[i * 4 + 1] * inv0,
                            acc0[i * 4 + 2] * inv0, acc0[i * 4 + 3] * inv0);
            *(float4*)&out[base + (size_t)gq1 * DD + i * 4] =
                make_float4(acc1[i * 4 + 0] * inv1, acc1[i * 4 + 1] * inv1,
                            acc1[i * 4 + 2] * inv1, acc1[i * 4 + 3] * inv1);
        }
    }

    float v1 = pr0_1 * inv0 + pr1_1 * inv1;
    float v2 = pr0_2 * inv0 + pr1_2 * inv1;
    float v3 = po0_1 * inv0 + po1_1 * inv1;
    float v4 = po0_2 * inv0 + po1_2 * inv1;
    #pragma unroll
    for (int off = 1; off < 64; off <<= 1) {
        v1 += __shfl_xor(v1, off);
        v2 += __shfl_xor(v2, off);
        v3 += __shfl_xor(v3, off);
        v4 += __shfl_xor(v4, off);
    }
    const int wv = t >> 6;
    if ((t & 63) == 0) { red4[0][wv] = v1; red4[1][wv] = v2; red4[2][wv] = v3; red4[3][wv] = v4; }
    __syncthreads();
    if (t < 4) {
        float s = red4[t][0] + red4[t][1] + red4[t][2] + red4[t][3];
        atomicAdd(&sums[t * 32], (double)s);
    }
}

// ---- variant B: grid-level 2-way K-split + merge ---------------------------
// Block bid = split*1024 + (b,h,qt). Split s handles contiguous tile range
// [s*htiles, min(ntiles,(s+1)*htiles)). Writes row state (m,l,4 sums, acc[32])
// as a 40-float record to part[(split*1024+bid0)*64+row]. No out writes here.
__global__ __launch_bounds__(256) void attn_split_kernel(
    const float* __restrict__ Q, const float* __restrict__ Kg, const float* __restrict__ Vg,
    const unsigned char* __restrict__ A8,
    const int* __restrict__ lengths, const float* __restrict__ alpha,
    float* __restrict__ part)
{
    const int bidAll = blockIdx.x;
    const int split = bidAll >> 10;
    const int bid = bidAll & 1023;
    const int qt = bid & 15;
    const int hh = (bid >> 4) & 7;
    const int b  = bid >> 7;
    const int t  = threadIdx.x;
    const int qg = t >> 3;
    const int lane8 = t & 7;

    const int len = lengths[b];
    const size_t base = ((size_t)b * HH + hh) * NN * DD;

    if (qt * QT >= len) return;     // merge zero-fills padded q-blocks

    __shared__ float Qs[QT][36];
    __shared__ float Ks[KT][36];
    __shared__ float Vs[KT][36];
    __shared__ unsigned char As[QT][80];

    const float al  = alpha[0];
    const float l2a = __log2f(al);
    const float scale = 0.17677669529663687f;

    const int sr = t >> 3;
    const int sc = ((t & 7) - sr) & 7;

    #pragma unroll
    for (int i = 0; i < 2; ++i) {
        int r = i * 32 + sr;
        float4 v = *(const float4*)&Q[base + (size_t)(qt * QT + r) * DD + sc * 4];
        v.x *= scale; v.y *= scale; v.z *= scale; v.w *= scale;
        *(float4*)&Qs[r][sc * 4] = v;
    }

    float m0 = -1e30f, m1 = -1e30f, l0 = 0.f, l1 = 0.f;
    float acc0[32], acc1[32];
    #pragma unroll
    for (int d = 0; d < 32; ++d) { acc0[d] = 0.f; acc1[d] = 0.f; }
    float pr0_1 = 0.f, pr0_2 = 0.f, po0_1 = 0.f, po0_2 = 0.f;
    float pr1_1 = 0.f, pr1_2 = 0.f, po1_1 = 0.f, po1_2 = 0.f;

    const int ntiles = (len + KT - 1) / KT;
    const int htiles = (ntiles + 1) >> 1;
    const int t0 = split * htiles;
    const int t1 = (ntiles < t0 + htiles) ? ntiles : (t0 + htiles);

    for (int tt = t0; tt < t1; ++tt) {
        const int j0 = tt * KT;     // always < len (real tiles only)
        __syncthreads();
        #pragma unroll
        for (int i = 0; i < 2; ++i) {
            int r = i * 32 + sr;
            *(float4*)&Ks[r][sc * 4] = *(const float4*)&Kg[base + (size_t)(j0 + r) * DD + sc * 4];
            *(float4*)&Vs[r][sc * 4] = *(const float4*)&Vg[base + (size_t)(j0 + r) * DD + sc * 4];
        }
        {
            int r = t >> 2, c = (t & 3) * 16;
            *(int4*)&As[r][c] = *(const int4*)&A8[((size_t)b * NN + qt * QT + r) * NN + j0 + c];
        }
        __syncthreads();

        float s0[8], s1[8];
        #pragma unroll
        for (int e = 0; e < 8; ++e) { s0[e] = 0.f; s1[e] = 0.f; }
        #pragma unroll
        for (int i = 0; i < 8; ++i) {
            float4 qa = *(const float4*)&Qs[qg][i * 4];
            float4 qb = *(const float4*)&Qs[qg + 32][i * 4];
            #pragma unroll
            for (int e = 0; e < 8; ++e) {
                float4 kv = *(const float4*)&Ks[e * 8 + lane8][i * 4];
                s0[e] = fmaf(qa.x, kv.x, s0[e]); s0[e] = fmaf(qa.y, kv.y, s0[e]);
                s0[e] = fmaf(qa.z, kv.z, s0[e]); s0[e] = fmaf(qa.w, kv.w, s0[e]);
                s1[e] = fmaf(qb.x, kv.x, s1[e]); s1[e] = fmaf(qb.y, kv.y, s1[e]);
                s1[e] = fmaf(qb.z, kv.z, s1[e]); s1[e] = fmaf(qb.w, kv.w, s1[e]);
            }
        }

        float tm0 = -INFINITY, tm1 = -INFINITY;
        #pragma unroll
        for (int e = 0; e < 8; ++e) {
            bool valid = (j0 + e * 8 + lane8) < len;
            s0[e] = valid ? s0[e] : -INFINITY;
            s1[e] = valid ? s1[e] : -INFINITY;
            tm0 = fmaxf(tm0, s0[e]); tm1 = fmaxf(tm1, s1[e]);
        }
        #pragma unroll
        for (int off = 1; off < 8; off <<= 1) {
            tm0 = fmaxf(tm0, __shfl_xor(tm0, off, 8));
            tm1 = fmaxf(tm1, __shfl_xor(tm1, off, 8));
        }
        if (tm0 > m0) {
            float scl = __expf(m0 - tm0);
            l0 *= scl; pr0_1 *= scl; pr0_2 *= scl; po0_1 *= scl; po0_2 *= scl;
            #pragma unroll
            for (int d = 0; d < 32; ++d) acc0[d] *= scl;
            m0 = tm0;
        }
        if (tm1 > m1) {
            float scl = __expf(m1 - tm1);
            l1 *= scl; pr1_1 *= scl; pr1_2 *= scl; po1_1 *= scl; po1_2 *= scl;
            #pragma unroll
            for (int d = 0; d < 32; ++d) acc1[d] *= scl;
            m1 = tm1;
        }

        #pragma unroll
        for (int e = 0; e < 8; ++e) {
            int j = e * 8 + lane8;
            float pe0 = __expf(s0[e] - m0);
            float pe1 = __expf(s1[e] - m1);
            l0 += pe0; l1 += pe1;
            int a0 = As[qg][j], a1 = As[qg + 32][j];
            float w0 = exp2f((float)a0 * l2a);
            float w1 = exp2f((float)a1 * l2a);
            float pw0 = pe0 * w0, pw1 = pe1 * w1;
            pr0_1 += (a0 == 1) ? pe0 : 0.f;  pr0_2 += (a0 > 1) ? pe0 : 0.f;
            po0_1 += (a0 == 1) ? pw0 : 0.f;  po0_2 += (a0 > 1) ? pw0 : 0.f;
            pr1_1 += (a1 == 1) ? pe1 : 0.f;  pr1_2 += (a1 > 1) ? pe1 : 0.f;
            po1_1 += (a1 == 1) ? pw1 : 0.f;  po1_2 += (a1 > 1) ? pw1 : 0.f;
            s0[e] = pw0; s1[e] = pw1;
        }

        #pragma unroll
        for (int e = 0; e < 8; ++e) {
            float pw0 = s0[e], pw1 = s1[e];
            #pragma unroll
            for (int i = 0; i < 8; ++i) {
                float4 vv = *(const float4*)&Vs[e * 8 + lane8][i * 4];
                acc0[i * 4 + 0] = fmaf(pw0, vv.x, acc0[i * 4 + 0]);
                acc0[i * 4 + 1] = fmaf(pw0, vv.y, acc0[i * 4 + 1]);
                acc0[i * 4 + 2] = fmaf(pw0, vv.z, acc0[i * 4 + 2]);
                acc0[i * 4 + 3] = fmaf(pw0, vv.w, acc0[i * 4 + 3]);
                acc1[i * 4 + 0] = fmaf(pw1, vv.x, acc1[i * 4 + 0]);
                acc1[i * 4 + 1] = fmaf(pw1, vv.y, acc1[i * 4 + 1]);
                acc1[i * 4 + 2] = fmaf(pw1, vv.z, acc1[i * 4 + 2]);
                acc1[i * 4 + 3] = fmaf(pw1, vv.w, acc1[i * 4 + 3]);
            }
        }
    }

    // reduce to row level across the 8-lane group (raw, pre-normalization)
    #pragma unroll
    for (int off = 1; off < 8; off <<= 1) {
        l0 += __shfl_xor(l0, off, 8);       l1 += __shfl_xor(l1, off, 8);
        pr0_1 += __shfl_xor(pr0_1, off, 8); pr0_2 += __shfl_xor(pr0_2, off, 8);
        po0_1 += __shfl_xor(po0_1, off, 8); po0_2 += __shfl_xor(po0_2, off, 8);
        pr1_1 += __shfl_xor(pr1_1, off, 8); pr1_2 += __shfl_xor(pr1_2, off, 8);
        po1_1 += __shfl_xor(po1_1, off, 8); po1_2 += __shfl_xor(po1_2, off, 8);
        #pragma unroll
        for (int d = 0; d < 32; ++d) {
            acc0[d] += __shfl_xor(acc0[d], off, 8);
            acc1[d] += __shfl_xor(acc1[d], off, 8);
        }
    }

    const int dsl = lane8 * 4;
    float* st0 = part + (((size_t)split * 1024 + bid) * 64 + qg) * 40;
    float* st1 = st0 + 32 * 40;
    if (lane8 == 0) {
        st0[0] = m0; st0[1] = l0; st0[2] = pr0_1; st0[3] = pr0_2; st0[4] = po0_1; st0[5] = po0_2;
        st1[0] = m1; st1[1] = l1; st1[2] = pr1_1; st1[3] = pr1_2; st1[4] = po1_1; st1[5] = po1_2;
    }
    *(float4*)&st0[8 + dsl] = make_float4(acc0[dsl], acc0[dsl + 1], acc0[dsl + 2], acc0[dsl + 3]);
    *(float4*)&st1[8 + dsl] = make_float4(acc1[dsl], acc1[dsl + 1], acc1[dsl + 2], acc1[dsl + 3]);
}

__global__ __launch_bounds__(256) void merge_kernel(
    const float* __restrict__ part, const int* __restrict__ lengths,
    float* __restrict__ out, double* __restrict__ sums)
{
    const int bid = blockIdx.x;
    const int qt = bid & 15;
    const int hh = (bid >> 4) & 7;
    const int b  = bid >> 7;
    const int t  = threadIdx.x;
    const int qg = t >> 3;
    const int lane8 = t & 7;
    const int dsl = lane8 * 4;
    const int len = lengths[b];
    const size_t base = ((size_t)b * HH + hh) * NN * DD;

    if (qt * QT >= len) {           // padded q-block: zeros (part never written)
        float4 z = make_float4(0.f, 0.f, 0.f, 0.f);
        *(float4*)&out[base + (size_t)(qt * QT + qg) * DD + dsl] = z;
        *(float4*)&out[base + (size_t)(qt * QT + qg + 32) * DD + dsl] = z;
        return;
    }

    float v1 = 0.f, v2 = 0.f, v3 = 0.f, v4 = 0.f;
    #pragma unroll
    for (int rr = 0; rr < 2; ++rr) {
        const int row = qg + rr * 32;
        const int gq = qt * QT + row;
        const float* sA = part + (((size_t)0 * 1024 + bid) * 64 + row) * 40;
        const float* sB = part + (((size_t)1 * 1024 + bid) * 64 + row) * 40;
        float mA = sA[0], lA = sA[1], mB = sB[0], lB = sB[1];
        float ms = fmaxf(mA, mB);
        float fA = __expf(mA - ms), fB = __expf(mB - ms);
        float L = lA * fA + lB * fB;
        float inv = (gq < len) ? 1.f / L : 0.f;
        float4 aA = *(const float4*)&sA[8 + dsl];
        float4 aB = *(const float4*)&sB[8 + dsl];
        float4 o;
        o.x = (aA.x * fA + aB.x * fB) * inv;
        o.y = (aA.y * fA + aB.y * fB) * inv;
        o.z = (aA.z * fA + aB.z * fB) * inv;
        o.w = (aA.w * fA + aB.w * fB) * inv;
        *(float4*)&out[base + (size_t)gq * DD + dsl] = o;
        if (lane8 == 0) {
            v1 += (sA[2] * fA + sB[2] * fB) * inv;
            v2 += (sA[3] * fA + sB[3] * fB) * inv;
            v3 += (sA[4] * fA + sB[4] * fB) * inv;
            v4 += (sA[5] * fA + sB[5] * fB) * inv;
        }
    }

    __shared__ float red4[4][4];
    #pragma unroll
    for (int off = 1; off < 64; off <<= 1) {
        v1 += __shfl_xor(v1, off);
        v2 += __shfl_xor(v2, off);
        v3 += __shfl_xor(v3, off);
        v4 += __shfl_xor(v4, off);
    }
    const int wv = t >> 6;
    if ((t & 63) == 0) { red4[0][wv] = v1; red4[1][wv] = v2; red4[2][wv] = v3; red4[3][wv] = v4; }
    __syncthreads();
    if (t < 4) {
        float s = red4[t][0] + red4[t][1] + red4[t][2] + red4[t][3];
        atomicAdd(&sums[t * 32], (double)s);
    }
}

__global__ void fin_kernel(const double* __restrict__ sums,
                           const unsigned long long* __restrict__ cnt,
                           float* __restrict__ outtail)
{
    if (threadIdx.x == 0) {
        double c1 = (double)(cnt[0] * (unsigned long long)HH);
        double c2 = (double)(cnt[32] * (unsigned long long)HH);
        outtail[0] = (float)(sums[0]  / c1);
        outtail[1] = (float)(sums[32] / c2);
        outtail[2] = (float)(sums[64] / c1);
        outtail[3] = (float)(sums[96] / c2);
    }
}

extern "C" void kernel_launch(void* const* d_in, const int* in_sizes, int n_in,
                              void* d_out, int out_size, void* d_ws, size_t ws_size,
                              hipStream_t stream)
{
    const float* h   = (const float*)d_in[0];
    const int* A     = (const int*)d_in[1];
    const int* lens  = (const int*)d_in[2];
    const float* alp = (const float*)d_in[3];
    const float* Wq  = (const float*)d_in[4];
    const float* bq  = (const float*)d_in[5];
    const float* Wk  = (const float*)d_in[6];
    const float* bk  = (const float*)d_in[7];
    const float* Wv  = (const float*)d_in[8];
    const float* bv  = (const float*)d_in[9];

    float* outF = (float*)d_out;

    const size_t qkv = (size_t)BB * HH * NN * DD;
    float* Qw = (float*)d_ws;
    float* Kw = Qw + qkv;
    float* Vw = Kw + qkv;
    unsigned char* A8 = (unsigned char*)(Vw + qkv);
    double* sums = (double*)(A8 + (size_t)BB * NN * NN);
    unsigned long long* cnt = (unsigned long long*)(sums + 128);
    float* part = (float*)(cnt + 64);

    const size_t need = (size_t)((char*)(part + (size_t)2048 * 64 * 40) - (char*)d_ws);

    (void)hipMemsetAsync(sums, 0, 128 * sizeof(double) + 64 * sizeof(unsigned long long), stream);

    proj_kernel<<<dim3(12, 128), 256, 0, stream>>>(h, Wq, bq, Wk, bk, Wv, bv, lens, Qw, Kw, Vw);
    pack_kernel<<<1024, 256, 0, stream>>>(A, A8, cnt);
    if (ws_size >= need) {
        attn_split_kernel<<<2048, 256, 0, stream>>>(Qw, Kw, Vw, A8, lens, alp, part);
        merge_kernel<<<1024, 256, 0, stream>>>(part, lens, outF, sums);
    } else {
        attn_kernel<<<1024, 256, 0, stream>>>(Qw, Kw, Vw, A8, lens, alp, outF, sums);
    }
    fin_kernel<<<1, 64, 0, stream>>>(sums, cnt, outF + qkv);
}